// Round 5
// baseline (399.712 us; speedup 1.0000x reference)
//
#include <hip/hip_runtime.h>
#include <stdint.h>

#define NGK   5
#define NFK   10
#define NWK   8
#define STEPW 16      // NG + NF + 1
#define NSEQ  512
#define FDIM  32
#define BIGV  1000000000.0f
#define LXST  17      // u32 stride per packed-f16 row (68 B) -> conflict-free b32 reads

#define INVGL 0.28853900817779268f   // 1/(gamma*ln2)
#define TWOI  0.57707801635558537f   // 2*INVGL
#define GLN2  3.4657359027997265f    // gamma*ln2
#define UBIG  (-BIGV * INVGL)

#define EXP2F(x) __builtin_amdgcn_exp2f(x)
#define LOG2F(x) __builtin_amdgcn_logf(x)   // maps to v_log_f32 = log2 (validated rounds 1-4)

typedef _Float16 h2 __attribute__((ext_vector_type(2)));
union U32H2 { uint32_t u; h2 h; };
union U32F  { uint32_t u; float f; };

__device__ __forceinline__ h2 as_h2(uint32_t u) { U32H2 c; c.u = u; return c.h; }

#if __has_builtin(__builtin_amdgcn_fdot2)
__device__ __forceinline__ float fdot2p(uint32_t a, uint32_t b, float c) {
    return __builtin_amdgcn_fdot2(as_h2(a), as_h2(b), c, false);
}
#else
__device__ __forceinline__ float fdot2p(uint32_t a, uint32_t b, float c) {
    h2 av = as_h2(a), bv = as_h2(b);
    return fmaf((float)av.y, (float)bv.y, fmaf((float)av.x, (float)bv.x, c));
}
#endif

// 32-elem f16 dot, f32 accumulate, 2 independent chains (same sequence used for
// norms and cross-dots so D[i][i] cancels to ~1e-5).
__device__ __forceinline__ float dot16(const uint32_t* a, const uint32_t* b) {
    float e0 = 0.f, e1 = 0.f;
    #pragma unroll
    for (int c = 0; c < 16; c += 2) {
        e0 = fdot2p(a[c],     b[c],     e0);
        e1 = fdot2p(a[c + 1], b[c + 1], e1);
    }
    return e0 + e1;
}

// lane n <- lane n-1 (DPP wave_shr:1 = 0x138); lane 0 -> 0, always overridden.
__device__ __forceinline__ float dpp_shr1_f(float v) {
    U32F c; c.f = v;
    c.u = (uint32_t)__builtin_amdgcn_update_dpp(0, (int)c.u, 0x138, 0xF, 0xF, true);
    return c.f;
}

// ONE WAVE per batch element; barrier-free anti-diagonal sweep.
// Lane l owns rows 8l..8l+7 (x in registers). At step s lane l computes column
// j = s-l of its 8 rows (8 serial cells). Cross-lane R hand-off via DPP.
// u = -R/(gamma*ln2); softmin: u' = Dd + max3 + log2(1 + 2^(med-max) + 2^(min-max)).
__global__ __launch_bounds__(64, 1) void sdtw_kernel(
    const float* __restrict__ data, const int* __restrict__ lens,
    float* __restrict__ dists)
{
    __shared__ __align__(16) uint32_t LXh[NSEQ * LXST];  // 34816 B packed f16
    __shared__ float LSQ[NSEQ];                          // 2 KB norms

    const int b  = blockIdx.x;
    const int wl = threadIdx.x;          // 0..63
    const float* xb = data + (size_t)b * (NSEQ * FDIM);

    // ---- stage: coalesced float4 -> f16 pack -> LDS (4096 float4 / 64 lanes) ----
    for (int r = 0; r < 64; ++r) {
        int q = r * 64 + wl;
        float4 v = ((const float4*)xb)[q];
        h2 p0; p0.x = (_Float16)v.x; p0.y = (_Float16)v.y;
        h2 p1; p1.x = (_Float16)v.z; p1.y = (_Float16)v.w;
        U32H2 c0; c0.h = p0; U32H2 c1; c1.h = p1;
        int row = q >> 3, c2 = (q & 7) * 2;
        LXh[row * LXST + c2]     = c0.u;
        LXh[row * LXST + c2 + 1] = c1.u;
    }
    __syncthreads();

    // ---- own 8 rows -> registers; norms -> LSQ ----
    uint32_t xi[8][16];
    float cq[8];
    #pragma unroll
    for (int q = 0; q < 8; ++q) {
        #pragma unroll
        for (int c = 0; c < 16; ++c) xi[q][c] = LXh[(8 * wl + q) * LXST + c];
        float sq = dot16(xi[q], xi[q]);
        LSQ[8 * wl + q] = sq;
        cq[q] = -INVGL * sq;
    }
    __syncthreads();

    int L = lens[b];
    L = L < 1 ? 1 : (L > NSEQ ? NSEQ : L);
    const int Lm8  = L - 8 * wl;               // cell q valid iff q < Lm8
    const int lout = (L - 1) >> 3, qout = (L - 1) & 7;
    const int smax = (L - 1) + lout;

    // DP state
    float u[8];
    #pragma unroll
    for (int q = 0; q < 8; ++q) u[q] = UBIG;
    if (wl == 0) u[0] = 0.0f;                  // virtual start: softmin picks R=0 path at (0,0)
    float a_prev = UBIG;                       // u of (8l-1, j-1)

    // x_j prefetch double-buffer; init for s=0 (j = -wl -> clamp 0)
    uint32_t XA[16], XB[16]; float SQA, SQB;
    #pragma unroll
    for (int c = 0; c < 16; ++c) XA[c] = LXh[c];
    SQA = LSQ[0];

#define STEP(XC, XN, SQC, SQN) {                                              \
    int jn = s + 1 - wl; jn = jn < 0 ? 0 : (jn > NSEQ - 1 ? NSEQ - 1 : jn);   \
    const int jbase = jn * LXST;                                              \
    _Pragma("unroll")                                                         \
    for (int c = 0; c < 16; ++c) XN[c] = LXh[jbase + c];                      \
    SQN = LSQ[jn];                                                            \
    const int j = s - wl;                                                     \
    const bool inr = (j >= 0) & (j < L);                                      \
    float bu = dpp_shr1_f(u[7]);                                              \
    bu = (wl == 0) ? UBIG : bu;                                               \
    const float msqI = -INVGL * SQC;                                          \
    float dprev = a_prev;                                                     \
    a_prev = bu;                                                              \
    float up = bu;                                                            \
    _Pragma("unroll")                                                         \
    for (int q = 0; q < 8; ++q) {                                             \
        float dot = dot16(xi[q], XC);                                         \
        float Dd  = fmaf(dot, TWOI, cq[q]) + msqI;     /* = -D*INVGL */       \
        float tmp = u[q];                              /* left pred (old) */  \
        float M  = fmaxf(fmaxf(dprev, up), tmp);                              \
        float md = __builtin_amdgcn_fmed3f(dprev, up, tmp);                   \
        float mn = fminf(fminf(dprev, up), tmp);                              \
        float e  = 1.0f + EXP2F(md - M) + EXP2F(mn - M);                      \
        float un = Dd + M + LOG2F(e);                                         \
        un   = (q < Lm8) ? un : UBIG;                                         \
        u[q] = inr ? un : u[q];                                               \
        dprev = tmp;                                                          \
        up    = u[q];                                                         \
    }                                                                         \
}

    int s = 0;
    for (;;) {
        STEP(XA, XB, SQA, SQB);
        if (++s > smax) break;
        STEP(XB, XA, SQB, SQA);
        if (++s > smax) break;
    }
#undef STEP

    if (wl == lout) {
        float uo = u[0];
        #pragma unroll
        for (int q = 1; q < 8; ++q) if (qout == q) uo = u[q];
        dists[b] = -uo * GLN2 * (0.5f / (float)L);   // R/(2L)
    }
}

// Tiny finalize: hard-triplet reduction over the 128 distances -> scalar
__global__ __launch_bounds__(64) void finalize_kernel(
    const float* __restrict__ dists, float* __restrict__ out)
{
    __shared__ float acc[NWK];
    const int t = threadIdx.x;
    const int g = NGK + 1;  // 6
    if (t < NWK) {
        float dd[STEPW];
        #pragma unroll
        for (int s = 0; s < STEPW; ++s) dd[s] = dists[t * STEPW + s];

        float sum_lks = 0.f, nnz = 0.f;
        for (int ii = 0; ii < g; ++ii) {
            float mx = 0.f;  // scores are relu'd (>=0), so 0 is a safe identity
            for (int jj = 0; jj < g; ++jj) {
                float dmg_ij = 0.5f * (dd[ii] + dd[jj]);
                for (int f = 0; f < NFK; ++f) {
                    float s = dmg_ij + 1.0f - 0.5f * (dd[ii] + dd[g + f]);
                    s = fmaxf(s, 0.f);
                    mx = fmaxf(mx, s);
                }
            }
            sum_lks += mx;
            nnz += (mx != 0.f) ? 1.f : 0.f;
        }
        sum_lks *= (float)(g * NFK);
        nnz     *= (float)(g * NFK);
        float lv = sum_lks / (nnz + 1.f);

        float only_pos = 0.f;
        for (int ii = 1; ii < g; ++ii)
            for (int jj = 0; jj < ii; ++jj)
                only_pos += 0.5f * (dd[ii] + dd[jj]);
        only_pos *= (0.01f / (float)NGK);  // MODEL_LAMBDA / NG

        acc[t] = lv + only_pos;
    }
    __syncthreads();
    if (t == 0) {
        float s = 0.f;
        #pragma unroll
        for (int w = 0; w < NWK; ++w) s += acc[w];
        out[0] = s * (1.0f / (float)NWK);
    }
}

extern "C" void kernel_launch(void* const* d_in, const int* in_sizes, int n_in,
                              void* d_out, int out_size, void* d_ws, size_t ws_size,
                              hipStream_t stream)
{
    const float* data = (const float*)d_in[0];   // (128, 512, 32) f32
    const int*   lens = (const int*)d_in[1];     // (128,) i32
    float* out   = (float*)d_out;                // scalar f32
    float* dists = (float*)d_ws;                 // 128 floats scratch

    const int B = NWK * STEPW;  // 128
    sdtw_kernel<<<B, 64, 0, stream>>>(data, lens, dists);
    finalize_kernel<<<1, 64, 0, stream>>>(dists, out);
}

// Round 6
// 140.621 us; speedup vs baseline: 2.8425x; 2.8425x over previous
//
#include <hip/hip_runtime.h>
#include <stdint.h>

#define NGK   5
#define NFK   10
#define NWK   8
#define STEPW 16      // NG + NF + 1
#define NSEQ  512
#define FDIM  32
#define NBAT  128
#define SROWS 576     // skewed D rows: (L-1)+(lout) <= 511+63 = 574
#define BIGV  1000000000.0f

#define INVGL 0.28853900817779268f   // 1/(gamma*ln2)
#define GLN2  3.4657359027997265f    // gamma*ln2

#define EXP2F(x) __builtin_amdgcn_exp2f(x)
#define LOG2F(x) __builtin_amdgcn_logf(x)   // v_log_f32 = log2 (validated r1-r5)

typedef _Float16 h2 __attribute__((ext_vector_type(2)));
typedef short    bf16x8 __attribute__((ext_vector_type(8)));
typedef float    f32x4  __attribute__((ext_vector_type(4)));

union U32H2 { uint32_t u; h2 h; };
union U32F  { uint32_t u; float f; };

__device__ __forceinline__ h2 as_h2(uint32_t u) { U32H2 c; c.u = u; return c.h; }
__device__ __forceinline__ uint32_t h2_as_u32(h2 h) { U32H2 c; c.h = h; return c.u; }
__device__ __forceinline__ uint32_t f2bf(float f) {  // f32 -> bf16 RNE
    U32F c; c.f = f;
    return (c.u + 0x7FFFu + ((c.u >> 16) & 1u)) >> 16;
}
__device__ __forceinline__ float bfbits_lo(uint32_t u) { U32F c; c.u = u << 16; return c.f; }
__device__ __forceinline__ float bfbits_hi(uint32_t u) { U32F c; c.u = u & 0xFFFF0000u; return c.f; }

// lane n <- lane n-1 (DPP wave_shr:1 = 0x138); lane 0 -> 0 (bound_ctrl), which
// is exactly the E-domain boundary value (E(BIG) == 0).
__device__ __forceinline__ float dpp_shr1_f(float v) {
    U32F c; c.f = v;
    c.u = (uint32_t)__builtin_amdgcn_update_dpp(0, (int)c.u, 0x138, 0xF, 0xF, true);
    return c.f;
}

// ---------------- kernel 1: x -> bf16 (row-major 64B rows) + row norms ----------------
__global__ __launch_bounds__(256, 1) void prep_kernel(
    const float* __restrict__ data, uint16_t* __restrict__ xbf,
    float* __restrict__ sq)
{
    __shared__ uint32_t LB[NSEQ * 16];   // 32 KB bf16-pair rows
    const int b = blockIdx.x;
    const int t = threadIdx.x;
    const float4* xb4 = (const float4*)(data + (size_t)b * (NSEQ * FDIM));
    uint2* xg = (uint2*)(xbf + (size_t)b * (NSEQ * FDIM));

    #pragma unroll
    for (int it = 0; it < 16; ++it) {
        int q = it * 256 + t;            // float4 index, 4096 total
        float4 v = xb4[q];
        uint32_t u0 = f2bf(v.x) | (f2bf(v.y) << 16);
        uint32_t u1 = f2bf(v.z) | (f2bf(v.w) << 16);
        LB[q * 2] = u0; LB[q * 2 + 1] = u1;
        uint2 st; st.x = u0; st.y = u1;
        xg[q] = st;
    }
    __syncthreads();
    #pragma unroll
    for (int rr = 0; rr < 2; ++rr) {
        int r = t + rr * 256;
        float acc = 0.f;
        #pragma unroll
        for (int c = 0; c < 16; ++c) {
            uint32_t u = LB[r * 16 + c];
            float lo = bfbits_lo(u), hi = bfbits_hi(u);
            acc = fmaf(lo, lo, acc);
            acc = fmaf(hi, hi, acc);
        }
        sq[(size_t)b * NSEQ + r] = acc;
    }
}

// ---------------- kernel 2: D generation via MFMA into skewed f16 layout ----------------
// Dsk[b][s][r] = D[r][s - (r>>3)]  (f16). Block = (tj, b), 4 waves; wave w does
// ti = 8w..8w+7 so stores of consecutive ti merge into full cache lines.
__global__ __launch_bounds__(256, 1) void dgen_kernel(
    const uint16_t* __restrict__ xbf, const float* __restrict__ sq,
    uint16_t* __restrict__ dsk)
{
    const int tj = blockIdx.x;           // 0..31
    const int b  = blockIdx.y;           // 0..127
    const int w  = threadIdx.x >> 6;     // 0..3
    const int lane = threadIdx.x & 63;
    const int rl = lane & 15, kq = lane >> 4;
    const int rr0 = kq * 4;              // C rows rr0..rr0+3 (validated layout)

    const short* xb = (const short*)(xbf + (size_t)b * (NSEQ * FDIM));
    const float* sqb = sq + (size_t)b * NSEQ;
    uint16_t* dskb = dsk + (size_t)b * (SROWS * NSEQ);

    bf16x8 bfrag = *(const bf16x8*)(xb + (tj * 16 + rl) * FDIM + kq * 8);
    float sqJ = sqb[tj * 16 + rl];

    #pragma unroll
    for (int it = 0; it < 8; ++it) {
        int ti = w * 8 + it;
        bf16x8 afrag = *(const bf16x8*)(xb + (ti * 16 + rl) * FDIM + kq * 8);
        f32x4 c = {0.f, 0.f, 0.f, 0.f};
        c = __builtin_amdgcn_mfma_f32_16x16x32_bf16(afrag, bfrag, c, 0, 0, 0);
        f32x4 s4 = *(const f32x4*)(sqb + ti * 16 + rr0);
        h2 p0, p1;
        p0.x = (_Float16)(s4[0] + sqJ - 2.f * c[0]);
        p0.y = (_Float16)(s4[1] + sqJ - 2.f * c[1]);
        p1.x = (_Float16)(s4[2] + sqJ - 2.f * c[2]);
        p1.y = (_Float16)(s4[3] + sqJ - 2.f * c[3]);
        int sr = tj * 16 + rl + ti * 2 + (rr0 >> 3);
        uint2 st; st.x = h2_as_u32(p0); st.y = h2_as_u32(p1);
        *(uint2*)(dskb + sr * NSEQ + ti * 16 + rr0) = st;
    }
}

// ---------------- kernel 3: exp-domain soft-DTW, one wave per batch ----------------
__global__ __launch_bounds__(64, 1) void dp_kernel(
    const uint16_t* __restrict__ dsk, const int* __restrict__ lens,
    float* __restrict__ dists)
{
    const int b = blockIdx.x;
    const int wl = threadIdx.x;
    const uint16_t* dskb = dsk + (size_t)b * (SROWS * NSEQ);

    int L = lens[b]; L = L < 1 ? 1 : (L > NSEQ ? NSEQ : L);
    const int Lm8 = L - 8 * wl;
    const int lout = (L - 1) >> 3, qout = (L - 1) & 7;
    const int smax = (L - 1) + lout;

    float E0 = 0.f, E1 = 0.f, E2 = 0.f, E3 = 0.f,
          E4 = 0.f, E5 = 0.f, E6 = 0.f, E7 = 0.f;
    if (wl == 0) E0 = 1.0f;   // virtual start: E(R=0) at (0,-1) position
    float ap = 0.f;           // E of (8wl-1, j-1)

    // 4-deep prefetch ring (rows s..s+3)
    uint4 r0 = *(const uint4*)&dskb[0 * NSEQ + wl * 8];
    uint4 r1 = *(const uint4*)&dskb[1 * NSEQ + wl * 8];
    uint4 r2 = *(const uint4*)&dskb[2 * NSEQ + wl * 8];
    uint4 r3 = *(const uint4*)&dskb[3 * NSEQ + wl * 8];

    float Wa[8], Wb[8];

#define CW(W, rg) { \
    h2 ha = as_h2(rg.x), hb = as_h2(rg.y), hc = as_h2(rg.z), hd = as_h2(rg.w); \
    W[0] = EXP2F(-INVGL * (float)ha.x); W[1] = EXP2F(-INVGL * (float)ha.y);   \
    W[2] = EXP2F(-INVGL * (float)hb.x); W[3] = EXP2F(-INVGL * (float)hb.y);   \
    W[4] = EXP2F(-INVGL * (float)hc.x); W[5] = EXP2F(-INVGL * (float)hc.y);   \
    W[6] = EXP2F(-INVGL * (float)hd.x); W[7] = EXP2F(-INVGL * (float)hd.y); }

    CW(Wa, r0);   // W for s=0

#define PHASE(WU, WN, RGN, RGL) {                                             \
    float bu = dpp_shr1_f(E7);          /* E of (8wl-1, j) */                 \
    CW(WN, RGN);                        /* W for step s+1 (off-chain) */      \
    int ld = s + 4; ld = ld > SROWS - 1 ? SROWS - 1 : ld;                     \
    RGL = *(const uint4*)&dskb[ld * NSEQ + wl * 8];                           \
    int j = s - wl;                                                           \
    if ((unsigned)j < (unsigned)L) {                                          \
        float S0 = ap + E0, S1 = E0 + E1, S2 = E1 + E2, S3 = E2 + E3;         \
        float S4 = E3 + E4, S5 = E4 + E5, S6 = E5 + E6, S7 = E6 + E7;         \
        float up = bu;                                                        \
        E0 = (0 < Lm8) ? (S0 + up) * WU[0] : 0.f; up = E0;                    \
        E1 = (1 < Lm8) ? (S1 + up) * WU[1] : 0.f; up = E1;                    \
        E2 = (2 < Lm8) ? (S2 + up) * WU[2] : 0.f; up = E2;                    \
        E3 = (3 < Lm8) ? (S3 + up) * WU[3] : 0.f; up = E3;                    \
        E4 = (4 < Lm8) ? (S4 + up) * WU[4] : 0.f; up = E4;                    \
        E5 = (5 < Lm8) ? (S5 + up) * WU[5] : 0.f; up = E5;                    \
        E6 = (6 < Lm8) ? (S6 + up) * WU[6] : 0.f; up = E6;                    \
        E7 = (7 < Lm8) ? (S7 + up) * WU[7] : 0.f;                             \
    }                                                                         \
    ap = bu;                                                                  \
}

    int s = 0;
    for (;;) {
        PHASE(Wa, Wb, r1, r0); if (++s > smax) break;
        PHASE(Wb, Wa, r2, r1); if (++s > smax) break;
        PHASE(Wa, Wb, r3, r2); if (++s > smax) break;
        PHASE(Wb, Wa, r0, r3); if (++s > smax) break;
    }
#undef PHASE
#undef CW

    if (wl == lout) {
        float eo = E0;
        if (qout == 1) eo = E1; if (qout == 2) eo = E2; if (qout == 3) eo = E3;
        if (qout == 4) eo = E4; if (qout == 5) eo = E5; if (qout == 6) eo = E6;
        if (qout == 7) eo = E7;
        dists[b] = -GLN2 * LOG2F(eo) * (0.5f / (float)L);
    }
}

// ---------------- fallback (round-1 proven kernel) if ws is too small ----------------
#define FXSTR 36
__global__ __launch_bounds__(512, 1) void sdtw_fb(
    const float* __restrict__ data, const int* __restrict__ lens,
    float* __restrict__ dists)
{
    __shared__ __align__(16) float LX[NSEQ * FXSTR];
    __shared__ float LSQ[NSEQ];
    __shared__ float RB[3][NSEQ + 2];

    const int b = blockIdx.x;
    const int t = threadIdx.x;
    const float* xb = data + (size_t)b * (NSEQ * FDIM);

    #pragma unroll
    for (int r = 0; r < 8; ++r) {
        int q = r * 512 + t;
        int j = q >> 3, c4 = (q & 7) << 2;
        float4 v = ((const float4*)xb)[q];
        *(float4*)&LX[j * FXSTR + c4] = v;
    }
    for (int idx = t; idx < 3 * (NSEQ + 2); idx += 512) ((float*)RB)[idx] = BIGV;
    __syncthreads();

    const int i = t;
    float4 xi[8];
    float sqi = 0.f;
    {
        const float* src = &LX[i * FXSTR];
        #pragma unroll
        for (int c = 0; c < 8; ++c) {
            float4 v = *(const float4*)&src[c * 4];
            xi[c] = v;
            sqi += v.x * v.x + v.y * v.y + v.z * v.z + v.w * v.w;
        }
        LSQ[i] = sqi;
    }
    int L = lens[b];
    L = L < 1 ? 1 : (L > NSEQ ? NSEQ : L);
    __syncthreads();

    float lastR = 0.0f;
    if (i == 0) {
        float dot = 0.f;
        #pragma unroll
        for (int c = 0; c < 8; ++c) {
            float4 v = xi[c];
            dot += v.x * v.x + v.y * v.y + v.z * v.z + v.w * v.w;
        }
        float d00 = sqi + sqi - 2.f * dot;
        lastR = d00;
        RB[0][1] = d00;
    }
    __syncthreads();

    float* b0 = RB[1]; float* b1 = RB[0]; float* b2 = RB[2];
    const int kend = 2 * L - 2;
    for (int k = 1; k <= kend; ++k) {
        int j = k - i;
        if (j >= 0 && j < L && i < L) {
            const float* xj = &LX[j * FXSTR];
            float d0 = 0.f, d1 = 0.f, d2 = 0.f, d3 = 0.f;
            #pragma unroll
            for (int c = 0; c < 8; ++c) {
                float4 v = *(const float4*)&xj[c * 4];
                d0 = fmaf(v.x, xi[c].x, d0);
                d1 = fmaf(v.y, xi[c].y, d1);
                d2 = fmaf(v.z, xi[c].z, d2);
                d3 = fmaf(v.w, xi[c].w, d3);
            }
            float dot = (d0 + d1) + (d2 + d3);
            float Dij = sqi + LSQ[j] - 2.f * dot;
            float a = b2[i], bb = b1[i], cc = b1[i + 1];
            float m = fminf(fminf(a, bb), cc);
            float e = EXP2F((m - a) * INVGL) + EXP2F((m - bb) * INVGL)
                    + EXP2F((m - cc) * INVGL);
            float r = Dij + m - GLN2 * LOG2F(e);
            b0[i + 1] = r;
            lastR = r;
        }
        __syncthreads();
        float* tmp = b2; b2 = b1; b1 = b0; b0 = tmp;
    }
    if (i == L - 1) dists[b] = lastR / (2.0f * (float)L);
}

// ---------------- finalize: hard-triplet reduction -> scalar ----------------
__global__ __launch_bounds__(64) void finalize_kernel(
    const float* __restrict__ dists, float* __restrict__ out)
{
    __shared__ float acc[NWK];
    const int t = threadIdx.x;
    const int g = NGK + 1;  // 6
    if (t < NWK) {
        float dd[STEPW];
        #pragma unroll
        for (int s = 0; s < STEPW; ++s) dd[s] = dists[t * STEPW + s];

        float sum_lks = 0.f, nnz = 0.f;
        for (int ii = 0; ii < g; ++ii) {
            float mx = 0.f;
            for (int jj = 0; jj < g; ++jj) {
                float dmg_ij = 0.5f * (dd[ii] + dd[jj]);
                for (int f = 0; f < NFK; ++f) {
                    float s = dmg_ij + 1.0f - 0.5f * (dd[ii] + dd[g + f]);
                    s = fmaxf(s, 0.f);
                    mx = fmaxf(mx, s);
                }
            }
            sum_lks += mx;
            nnz += (mx != 0.f) ? 1.f : 0.f;
        }
        sum_lks *= (float)(g * NFK);
        nnz     *= (float)(g * NFK);
        float lv = sum_lks / (nnz + 1.f);

        float only_pos = 0.f;
        for (int ii = 1; ii < g; ++ii)
            for (int jj = 0; jj < ii; ++jj)
                only_pos += 0.5f * (dd[ii] + dd[jj]);
        only_pos *= (0.01f / (float)NGK);

        acc[t] = lv + only_pos;
    }
    __syncthreads();
    if (t == 0) {
        float s = 0.f;
        #pragma unroll
        for (int w = 0; w < NWK; ++w) s += acc[w];
        out[0] = s * (1.0f / (float)NWK);
    }
}

extern "C" void kernel_launch(void* const* d_in, const int* in_sizes, int n_in,
                              void* d_out, int out_size, void* d_ws, size_t ws_size,
                              hipStream_t stream)
{
    const float* data = (const float*)d_in[0];   // (128, 512, 32) f32
    const int*   lens = (const int*)d_in[1];     // (128,) i32
    float* out   = (float*)d_out;
    float* dists = (float*)d_ws;                 // 128 f32 at offset 0

    const size_t OFF_XBF = 1024;
    const size_t OFF_SQ  = OFF_XBF + (size_t)NBAT * NSEQ * FDIM * 2;   // +4 MB
    const size_t OFF_DSK = OFF_SQ  + (size_t)NBAT * NSEQ * 4;          // +256 KB
    const size_t NEED    = OFF_DSK + (size_t)NBAT * SROWS * NSEQ * 2;  // +75.5 MB

    if (ws_size >= NEED) {
        uint16_t* xbf = (uint16_t*)((char*)d_ws + OFF_XBF);
        float*    sq  = (float*)((char*)d_ws + OFF_SQ);
        uint16_t* dsk = (uint16_t*)((char*)d_ws + OFF_DSK);
        prep_kernel<<<NBAT, 256, 0, stream>>>(data, xbf, sq);
        dgen_kernel<<<dim3(32, NBAT), 256, 0, stream>>>(xbf, sq, dsk);
        dp_kernel<<<NBAT, 64, 0, stream>>>(dsk, lens, dists);
    } else {
        sdtw_fb<<<NBAT, 512, 0, stream>>>(data, lens, dists);
    }
    finalize_kernel<<<1, 64, 0, stream>>>(dists, out);
}

// Round 7
// 127.611 us; speedup vs baseline: 3.1323x; 1.1020x over previous
//
#include <hip/hip_runtime.h>
#include <stdint.h>

#define NGK   5
#define NFK   10
#define NWK   8
#define STEPW 16      // NG + NF + 1
#define NSEQ  512
#define FDIM  32
#define NBAT  128
#define SROWS 576     // skewed rows: max real row = 511 + 63 = 574
#define BIGV  1000000000.0f

#define INVGL 0.28853900817779268f   // 1/(gamma*ln2)
#define GLN2  3.4657359027997265f    // gamma*ln2

#define EXP2F(x) __builtin_amdgcn_exp2f(x)
#define LOG2F(x) __builtin_amdgcn_logf(x)   // v_log_f32 = log2 (validated r1-r6)

typedef short bf16x8 __attribute__((ext_vector_type(8)));
typedef float f32x4  __attribute__((ext_vector_type(4)));
union U32F { uint32_t u; float f; };

__device__ __forceinline__ uint32_t f2bf(float f) {  // f32 -> bf16 RNE
    U32F c; c.f = f;
    return (c.u + 0x7FFFu + ((c.u >> 16) & 1u)) >> 16;
}
__device__ __forceinline__ float bflo(uint32_t u) { U32F c; c.u = u << 16; return c.f; }
__device__ __forceinline__ float bfhi(uint32_t u) { U32F c; c.u = u & 0xFFFF0000u; return c.f; }

// lane n <- lane n-1 (DPP wave_shr:1 = 0x138); lane 0 -> 0 (= E-domain boundary).
__device__ __forceinline__ float dpp_shr1_f(float v) {
    U32F c; c.f = v;
    c.u = (uint32_t)__builtin_amdgcn_update_dpp(0, (int)c.u, 0x138, 0xF, 0xF, true);
    return c.f;
}

// ---------- kernel 1: fused stage + norms + MFMA -> skewed bf16 W matrix ----------
// Wsk[b][s][i] = 2^(-D[i][ s-(i>>3) ] * INVGL), clamped to 0 where i>=L or j>=L.
// Block (tj, b): B-cols tj*16..+15; 4 waves sweep ti tiles. Skips tiles whose
// skewed rows exceed maxrow = min(smax+8, 575) (dp never reads beyond).
__global__ __launch_bounds__(256, 1) void dgen_kernel(
    const float* __restrict__ data, const int* __restrict__ lens,
    uint16_t* __restrict__ wsk)
{
    __shared__ __align__(16) uint32_t XB[NSEQ * 20];   // 40 KB bf16-pair rows (pad 20)
    __shared__ __align__(16) float SQP[NSEQ][8];       // 16 KB norm partials
    __shared__ __align__(16) float SQ[NSEQ];           // 2 KB norms

    const int tj = blockIdx.x, b = blockIdx.y;
    const int t = threadIdx.x;
    int L = lens[b]; L = L < 1 ? 1 : (L > NSEQ ? NSEQ : L);
    const int smax = (L - 1) + ((L - 1) >> 3);
    int maxrow = smax + 8; if (maxrow > SROWS - 1) maxrow = SROWS - 1;
    if (tj * 16 > maxrow) return;   // block writes rows >= tj*16 only

    // stage: f32 -> bf16 pack -> LDS; norm partials per 1/8-row
    const float4* xb4 = (const float4*)(data + (size_t)b * (NSEQ * FDIM));
    #pragma unroll
    for (int it = 0; it < 16; ++it) {
        int q = it * 256 + t;                 // float4 index, 4096 total
        float4 v = xb4[q];
        uint32_t u0 = f2bf(v.x) | (f2bf(v.y) << 16);
        uint32_t u1 = f2bf(v.z) | (f2bf(v.w) << 16);
        int row = q >> 3, c2 = (q & 7) * 2;
        XB[row * 20 + c2]     = u0;
        XB[row * 20 + c2 + 1] = u1;
        float l0 = bflo(u0), h0 = bfhi(u0), l1 = bflo(u1), h1 = bfhi(u1);
        SQP[row][q & 7] = l0 * l0 + h0 * h0 + l1 * l1 + h1 * h1;
    }
    __syncthreads();
    #pragma unroll
    for (int rr = 0; rr < 2; ++rr) {
        int r = t + rr * 256;
        float a = 0.f;
        #pragma unroll
        for (int p = 0; p < 8; ++p) a += SQP[r][p];
        SQ[r] = a;
    }
    __syncthreads();

    const int w = t >> 6, lane = t & 63, rl = lane & 15, kq = lane >> 4, rr0 = kq * 4;
    const int j = tj * 16 + rl;
    bf16x8 bfrag = *(const bf16x8*)((const char*)XB + (size_t)j * 80 + kq * 16);
    float sqJ = SQ[j];
    const bool jok = j < L;
    uint16_t* wb = wsk + (size_t)b * (SROWS * NSEQ);

    for (int it = 0; it < 8; ++it) {
        int ti = w * 8 + it;
        if (tj * 16 + ti * 2 > maxrow) break;      // wave-uniform
        bf16x8 afrag = *(const bf16x8*)((const char*)XB + (size_t)(ti * 16 + rl) * 80 + kq * 16);
        f32x4 c = {0.f, 0.f, 0.f, 0.f};
        c = __builtin_amdgcn_mfma_f32_16x16x32_bf16(afrag, bfrag, c, 0, 0, 0);
        f32x4 s4 = *(const f32x4*)&SQ[ti * 16 + rr0];
        float wv[4];
        #pragma unroll
        for (int q2 = 0; q2 < 4; ++q2) {
            int i = ti * 16 + rr0 + q2;
            float dv = s4[q2] + sqJ - 2.f * c[q2];
            float e = EXP2F(-INVGL * dv);
            wv[q2] = (jok && (i < L)) ? e : 0.f;
        }
        int sr = j + ti * 2 + (rr0 >> 3);          // skewed row
        uint2 st;
        st.x = f2bf(wv[0]) | (f2bf(wv[1]) << 16);
        st.y = f2bf(wv[2]) | (f2bf(wv[3]) << 16);
        *(uint2*)(wb + (size_t)sr * NSEQ + ti * 16 + rr0) = st;
    }
}

// ---------- kernel 2: exp-domain soft-DTW, one wave per batch, branchless ----------
// E = 2^(-R*INVGL); E' = (E_diag + E_up + E_left) * W. Lane wl owns rows
// 8wl..8wl+7; per step one column j = s - wl; chain = 8 FMAs. Out-of-band and
// unwritten (poison) cells are provably benign: E stays exactly 0 pre-band
// (all inputs 0), W==0 post-band, and late-arriving garbage can first reach
// the output lane at step 575 > smax <= 574.
__global__ __launch_bounds__(64, 1) void dp_kernel(
    const uint16_t* __restrict__ wsk, const int* __restrict__ lens,
    float* __restrict__ dists)
{
    const int b = blockIdx.x, wl = threadIdx.x;
    const uint16_t* wb = wsk + (size_t)b * (SROWS * NSEQ) + wl * 8;
    int L = lens[b]; L = L < 1 ? 1 : (L > NSEQ ? NSEQ : L);
    const int lout = (L - 1) >> 3, qout = (L - 1) & 7, smax = (L - 1) + lout;

    float E0 = 0.f, E1 = 0.f, E2 = 0.f, E3 = 0.f,
          E4 = 0.f, E5 = 0.f, E6 = 0.f, E7 = 0.f;
    float ap = (wl == 0) ? 1.0f : 0.f;   // virtual start: diag pred of (0,0) = exp(0)

    // 8-deep register prefetch ring (rows s..s+7); rows 0..8 always written
    uint4 rg0 = *(const uint4*)(wb + 0 * NSEQ);
    uint4 rg1 = *(const uint4*)(wb + 1 * NSEQ);
    uint4 rg2 = *(const uint4*)(wb + 2 * NSEQ);
    uint4 rg3 = *(const uint4*)(wb + 3 * NSEQ);
    uint4 rg4 = *(const uint4*)(wb + 4 * NSEQ);
    uint4 rg5 = *(const uint4*)(wb + 5 * NSEQ);
    uint4 rg6 = *(const uint4*)(wb + 6 * NSEQ);
    uint4 rg7 = *(const uint4*)(wb + 7 * NSEQ);

    int s = 0;

#define PHASE(RG) {                                                           \
    float bu = dpp_shr1_f(E7);                                                \
    float w0 = bflo(RG.x), w1 = bfhi(RG.x), w2 = bflo(RG.y), w3 = bfhi(RG.y); \
    float w4 = bflo(RG.z), w5 = bfhi(RG.z), w6 = bflo(RG.w), w7 = bfhi(RG.w); \
    int ld = s + 8; if (ld > SROWS - 1) ld = SROWS - 1;                       \
    RG = *(const uint4*)(wb + (size_t)ld * NSEQ);                             \
    float A0 = (ap + E0) * w0, A1 = (E0 + E1) * w1;                           \
    float A2 = (E1 + E2) * w2, A3 = (E2 + E3) * w3;                           \
    float A4 = (E3 + E4) * w4, A5 = (E4 + E5) * w5;                           \
    float A6 = (E5 + E6) * w6, A7 = (E6 + E7) * w7;                           \
    E0 = fmaf(bu, w0, A0);                                                    \
    E1 = fmaf(E0, w1, A1);                                                    \
    E2 = fmaf(E1, w2, A2);                                                    \
    E3 = fmaf(E2, w3, A3);                                                    \
    E4 = fmaf(E3, w4, A4);                                                    \
    E5 = fmaf(E4, w5, A5);                                                    \
    E6 = fmaf(E5, w6, A6);                                                    \
    E7 = fmaf(E6, w7, A7);                                                    \
    ap = bu; ++s;                                                             \
}

    for (;;) {
        PHASE(rg0); if (s > smax) break;
        PHASE(rg1); if (s > smax) break;
        PHASE(rg2); if (s > smax) break;
        PHASE(rg3); if (s > smax) break;
        PHASE(rg4); if (s > smax) break;
        PHASE(rg5); if (s > smax) break;
        PHASE(rg6); if (s > smax) break;
        PHASE(rg7); if (s > smax) break;
    }
#undef PHASE

    if (wl == lout) {
        float eo = E0;
        if (qout == 1) eo = E1; if (qout == 2) eo = E2; if (qout == 3) eo = E3;
        if (qout == 4) eo = E4; if (qout == 5) eo = E5; if (qout == 6) eo = E6;
        if (qout == 7) eo = E7;
        dists[b] = -GLN2 * LOG2F(eo) * (0.5f / (float)L);
    }
}

// ---------------- fallback (round-1 proven kernel) if ws is too small ----------------
#define FXSTR 36
__global__ __launch_bounds__(512, 1) void sdtw_fb(
    const float* __restrict__ data, const int* __restrict__ lens,
    float* __restrict__ dists)
{
    __shared__ __align__(16) float LX[NSEQ * FXSTR];
    __shared__ float LSQ[NSEQ];
    __shared__ float RB[3][NSEQ + 2];

    const int b = blockIdx.x;
    const int t = threadIdx.x;
    const float* xb = data + (size_t)b * (NSEQ * FDIM);

    #pragma unroll
    for (int r = 0; r < 8; ++r) {
        int q = r * 512 + t;
        int j = q >> 3, c4 = (q & 7) << 2;
        float4 v = ((const float4*)xb)[q];
        *(float4*)&LX[j * FXSTR + c4] = v;
    }
    for (int idx = t; idx < 3 * (NSEQ + 2); idx += 512) ((float*)RB)[idx] = BIGV;
    __syncthreads();

    const int i = t;
    float4 xi[8];
    float sqi = 0.f;
    {
        const float* src = &LX[i * FXSTR];
        #pragma unroll
        for (int c = 0; c < 8; ++c) {
            float4 v = *(const float4*)&src[c * 4];
            xi[c] = v;
            sqi += v.x * v.x + v.y * v.y + v.z * v.z + v.w * v.w;
        }
        LSQ[i] = sqi;
    }
    int L = lens[b];
    L = L < 1 ? 1 : (L > NSEQ ? NSEQ : L);
    __syncthreads();

    float lastR = 0.0f;
    if (i == 0) {
        float dot = 0.f;
        #pragma unroll
        for (int c = 0; c < 8; ++c) {
            float4 v = xi[c];
            dot += v.x * v.x + v.y * v.y + v.z * v.z + v.w * v.w;
        }
        float d00 = sqi + sqi - 2.f * dot;
        lastR = d00;
        RB[0][1] = d00;
    }
    __syncthreads();

    float* b0 = RB[1]; float* b1 = RB[0]; float* b2 = RB[2];
    const int kend = 2 * L - 2;
    for (int k = 1; k <= kend; ++k) {
        int j = k - i;
        if (j >= 0 && j < L && i < L) {
            const float* xj = &LX[j * FXSTR];
            float d0 = 0.f, d1 = 0.f, d2 = 0.f, d3 = 0.f;
            #pragma unroll
            for (int c = 0; c < 8; ++c) {
                float4 v = *(const float4*)&xj[c * 4];
                d0 = fmaf(v.x, xi[c].x, d0);
                d1 = fmaf(v.y, xi[c].y, d1);
                d2 = fmaf(v.z, xi[c].z, d2);
                d3 = fmaf(v.w, xi[c].w, d3);
            }
            float dot = (d0 + d1) + (d2 + d3);
            float Dij = sqi + LSQ[j] - 2.f * dot;
            float a = b2[i], bb = b1[i], cc = b1[i + 1];
            float m = fminf(fminf(a, bb), cc);
            float e = EXP2F((m - a) * INVGL) + EXP2F((m - bb) * INVGL)
                    + EXP2F((m - cc) * INVGL);
            float r = Dij + m - GLN2 * LOG2F(e);
            b0[i + 1] = r;
            lastR = r;
        }
        __syncthreads();
        float* tmp = b2; b2 = b1; b1 = b0; b0 = tmp;
    }
    if (i == L - 1) dists[b] = lastR / (2.0f * (float)L);
}

// ---------------- finalize: hard-triplet reduction -> scalar ----------------
__global__ __launch_bounds__(64) void finalize_kernel(
    const float* __restrict__ dists, float* __restrict__ out)
{
    __shared__ float acc[NWK];
    const int t = threadIdx.x;
    const int g = NGK + 1;  // 6
    if (t < NWK) {
        float dd[STEPW];
        #pragma unroll
        for (int s = 0; s < STEPW; ++s) dd[s] = dists[t * STEPW + s];

        float sum_lks = 0.f, nnz = 0.f;
        for (int ii = 0; ii < g; ++ii) {
            float mx = 0.f;
            for (int jj = 0; jj < g; ++jj) {
                float dmg_ij = 0.5f * (dd[ii] + dd[jj]);
                for (int f = 0; f < NFK; ++f) {
                    float s = dmg_ij + 1.0f - 0.5f * (dd[ii] + dd[g + f]);
                    s = fmaxf(s, 0.f);
                    mx = fmaxf(mx, s);
                }
            }
            sum_lks += mx;
            nnz += (mx != 0.f) ? 1.f : 0.f;
        }
        sum_lks *= (float)(g * NFK);
        nnz     *= (float)(g * NFK);
        float lv = sum_lks / (nnz + 1.f);

        float only_pos = 0.f;
        for (int ii = 1; ii < g; ++ii)
            for (int jj = 0; jj < ii; ++jj)
                only_pos += 0.5f * (dd[ii] + dd[jj]);
        only_pos *= (0.01f / (float)NGK);

        acc[t] = lv + only_pos;
    }
    __syncthreads();
    if (t == 0) {
        float s = 0.f;
        #pragma unroll
        for (int w = 0; w < NWK; ++w) s += acc[w];
        out[0] = s * (1.0f / (float)NWK);
    }
}

extern "C" void kernel_launch(void* const* d_in, const int* in_sizes, int n_in,
                              void* d_out, int out_size, void* d_ws, size_t ws_size,
                              hipStream_t stream)
{
    const float* data = (const float*)d_in[0];   // (128, 512, 32) f32
    const int*   lens = (const int*)d_in[1];     // (128,) i32
    float* out   = (float*)d_out;
    float* dists = (float*)d_ws;                 // 128 f32 at offset 0

    const size_t OFF_WSK = 1024;
    const size_t NEED = OFF_WSK + (size_t)NBAT * SROWS * NSEQ * 2;  // ~75.5 MB

    if (ws_size >= NEED) {
        uint16_t* wsk = (uint16_t*)((char*)d_ws + OFF_WSK);
        dgen_kernel<<<dim3(32, NBAT), 256, 0, stream>>>(data, lens, wsk);
        dp_kernel<<<NBAT, 64, 0, stream>>>(wsk, lens, dists);
    } else {
        sdtw_fb<<<NBAT, 512, 0, stream>>>(data, lens, dists);
    }
    finalize_kernel<<<1, 64, 0, stream>>>(dists, out);
}